// Round 13
// baseline (128.307 us; speedup 1.0000x reference)
//
#include <hip/hip_runtime.h>
#include <math.h>

#define BBATCH 64
#define LL 200
#define DD 300
#define PP 16
#define EPSV 1e-12f
#define KG 320          // global K-pad (10 chunks of 32)
#define PS 328          // maxsim LDS row stride in halfs (656 B: 4-bank row shift)
#define NCH 10

typedef _Float16 f16x8 __attribute__((ext_vector_type(8)));
typedef float f32x4v __attribute__((ext_vector_type(4)));

// ---------------- ksq: one-block micro-kernel builds the k^2 frag table -----------------
// Replaces per-prep-block rebuild (was 896 x 1280 scattered 16B kern loads). Coalesced
// stage -> LDS -> 640 f16x8 entries: ksqt[(ch*4+quad)*16+p][e] = f16(kern[p][ch*32+quad*8+e]^2)
__global__ __launch_bounds__(256) void ksq_kernel(const float* __restrict__ kern,
                                                  _Float16* __restrict__ ksqt) {
    __shared__ float kl[16][320];   // 20.5 KB, cols 300..319 zeroed
    const int t = threadIdx.x;
    for (int idx = t; idx < 16 * 75; idx += 256) {
        int p = idx / 75, c4 = (idx - p * 75) * 4;
        *(float4*)&kl[p][c4] = *(const float4*)&kern[p * DD + c4];
    }
    for (int idx = t; idx < 16 * 20; idx += 256) {
        int p = idx / 20, cc = 300 + (idx - p * 20);
        kl[p][cc] = 0.f;
    }
    __syncthreads();
    for (int ent = t; ent < 640; ent += 256) {
        int ch = ent >> 6, rem = ent & 63;
        int quad = rem >> 4, p = rem & 15;
        int k0 = ch * 32 + quad * 8;
        float4 a = *(const float4*)&kl[p][k0];
        float4 d = *(const float4*)&kl[p][k0 + 4];
        f16x8 h;
        h[0] = (_Float16)(a.x * a.x); h[1] = (_Float16)(a.y * a.y);
        h[2] = (_Float16)(a.z * a.z); h[3] = (_Float16)(a.w * a.w);
        h[4] = (_Float16)(d.x * d.x); h[5] = (_Float16)(d.y * d.y);
        h[6] = (_Float16)(d.z * d.z); h[7] = (_Float16)(d.w * d.w);
        *(f16x8*)&ksqt[(size_t)ent * 8] = h;
    }
}

// ---------------- prep: ZERO-LDS emit-during-staging + MFMA norms from L1 ----------------
// r12 diagnosis: prep ~45 us vs ~13 us HBM floor. Old structure: f32 LDS round-trip,
// emit on 2/4 waves, per-block scattered kern rebuild, 3 blocks/CU. New: (1) all threads
// read s coalesced (float4), convert, write h DIRECTLY (no LDS); (2) __syncthreads drains
// vmcnt -> h visible block-wide; (3) waves 0-1 run the proven 10-MFMA norm chain reading
// A-frags from just-written h (L1-hot) and B-frags from ksqt (L2-hot 10 KB, coalesced).
// Zero LDS -> 8 blocks/CU (32-wave cap). Invalid rows (grp 6): read-clamped to row 199,
// write-guarded; MFMA output rows are independent so garbage never contaminates valid rows.
// Precision: sa = f16(s)*f16(s) in f16 (was f16(s^2)) - same 2^-11 error order, f32 accum.
__global__ __launch_bounds__(256) void prep_kernel(const float* __restrict__ s1,
                                                   const float* __restrict__ s2,
                                                   float* __restrict__ n1inv,
                                                   _Float16* __restrict__ n2inv,
                                                   _Float16* __restrict__ h1,
                                                   _Float16* __restrict__ h2,
                                                   const _Float16* __restrict__ ksqt) {
    const int grp   = blockIdx.x;   // 0..6 (32-row groups)
    const int which = blockIdx.y;
    const int b     = blockIdx.z;
    const float* s  = which ? s2 : s1;
    _Float16* hout  = which ? h2 : h1;
    const int r0    = grp * 32;
    const int t     = threadIdx.x;

    // stage+emit: 32 rows x 40 f16x8 units, straight global->global
    for (int idx = t; idx < 32 * 40; idx += 256) {
        int r = idx / 40, q = idx - r * 40;
        int row = r0 + r;
        if (row >= LL) continue;
        int q8 = q * 8;
        const float* src = &s[((size_t)b * LL + row) * DD];
        f16x8 h;
        if (q8 + 8 <= DD) {            // q <= 36: fully in-range
            float4 a = *(const float4*)&src[q8];
            float4 d = *(const float4*)&src[q8 + 4];
            h[0] = (_Float16)a.x; h[1] = (_Float16)a.y; h[2] = (_Float16)a.z; h[3] = (_Float16)a.w;
            h[4] = (_Float16)d.x; h[5] = (_Float16)d.y; h[6] = (_Float16)d.z; h[7] = (_Float16)d.w;
        } else if (q8 < DD) {          // q == 37: elements 296..299 valid, 300..303 zero
            float4 a = *(const float4*)&src[q8];
            h[0] = (_Float16)a.x; h[1] = (_Float16)a.y; h[2] = (_Float16)a.z; h[3] = (_Float16)a.w;
            h[4] = (_Float16)0.f; h[5] = (_Float16)0.f; h[6] = (_Float16)0.f; h[7] = (_Float16)0.f;
        } else {                       // q >= 38: pure pad
#pragma unroll
            for (int e = 0; e < 8; e++) h[e] = (_Float16)0.f;
        }
        *(f16x8*)&hout[((size_t)b * LL + row) * KG + q8] = h;
    }
    __syncthreads();   // drains vmcnt(0): h writes visible to all waves in this block

    const int lane = t & 63;
    const int w    = t >> 6;
    if (w < 2) {
        // norms via MFMA: row group rg = w (16 rows each)
        const int rg   = w;
        const int c    = lane & 15;
        const int quad = lane >> 4;
        int arow = r0 + rg * 16 + c;
        int rowc = arow < LL ? arow : LL - 1;          // clamp: avoid OOB, results discarded
        const _Float16* hb = &hout[((size_t)b * LL + rowc) * KG];
        f32x4v nacc = (f32x4v)0.f;
#pragma unroll
        for (int ch = 0; ch < NCH; ch++) {
            f16x8 av = *(const f16x8*)&hb[ch * 32 + quad * 8];
            f16x8 sa = av * av;                        // 4 v_pk_mul_f16
            f16x8 bk = *(const f16x8*)&ksqt[((size_t)(ch * 4 + quad) * 16 + c) * 8];
            nacc = __builtin_amdgcn_mfma_f32_16x16x32_f16(sa, bk, nacc, 0, 0, 0);
        }
        // C/D: col = lane&15 = p, row = quad*4+r = local i
#pragma unroll
        for (int r = 0; r < 4; r++) {
            int row = r0 + rg * 16 + quad * 4 + r;
            if (row < LL) {
                float inv = 1.0f / sqrtf(fmaxf(nacc[r], EPSV));
                if (which) n2inv[((size_t)b * LL + row) * PP + c] = (_Float16)inv;
                else       n1inv[((size_t)b * LL + row) * PP + c] = inv;
            }
        }
    }
}

// ---------------- maxsim: full-j, UNROLL-CONTROLLED pass loop, fused n1inv epilogue ------
// (UNCHANGED from r12: 49.3 us, VGPR 188, spill-free, FETCH 8.7 MB.)
__global__ __launch_bounds__(256, 1) void maxsim_kernel(const _Float16* __restrict__ h1,
                                                        const _Float16* __restrict__ h2,
                                                        const _Float16* __restrict__ ksqt,
                                                        const _Float16* __restrict__ n2inv,
                                                        const float* __restrict__ n1inv,
                                                        float* __restrict__ out) {
    extern __shared__ __align__(16) char smem[];
    _Float16* h2s = (_Float16*)smem;          // 200*PS halfs = 131,200 B
    _Float16* n2s = h2s + 200 * PS;           // 200*16 halfs =   6,400 B
    _Float16* kqs = n2s + 200 * PP;           // 5120 halfs   =  10,240 B (total 147,840)

    const int blk  = blockIdx.x;
    const int b    = blk & 63;
    const int v    = blk >> 6;                // 0..3
    const int iblk = v & 1;
    const int pgrp = v >> 1;
    const int i0   = iblk ? 72 : 0;
    const int t    = threadIdx.x;

    const int lane = t & 63;
    const int w    = t >> 6;                  // 4 waves
    const int c    = lane & 15;
    const int quad = lane >> 4;
    const int ibase = i0 + w * 32;

    // A fragments: global -> registers (20 x b128 = 80 VGPR; h1 is L2/L3-hot)
    f16x8 af[2][NCH];
    {
        const _Float16* g1 = h1 + (size_t)b * LL * KG;
#pragma unroll
        for (int it = 0; it < 2; it++)
#pragma unroll
            for (int ch = 0; ch < NCH; ch++)
                af[it][ch] = *(const f16x8*)&g1[(size_t)(ibase + it * 16 + c) * KG + ch * 32 + quad * 8];
    }

    // stage FULL B tile (200 rows) + n2 (200 rows) + ksq table into LDS
    {
        const _Float16* g2 = h2 + (size_t)b * LL * KG;
        for (int idx = t; idx < 200 * 40; idx += 256) {
            int r = idx / 40, q = idx - r * 40;
            *(f16x8*)&h2s[r * PS + q * 8] = *(const f16x8*)&g2[(size_t)idx * 8];
        }
        const _Float16* gn = n2inv + (size_t)b * LL * PP;
        for (int idx = t; idx < 400; idx += 256)
            *(f16x8*)&n2s[idx * 8] = *(const f16x8*)&gn[(size_t)idx * 8];
        for (int idx = t; idx < 640; idx += 256)
            *(f16x8*)&kqs[idx * 8] = *(const f16x8*)&ksqt[(size_t)idx * 8];
    }
    __syncthreads();

    for (int pp = 0; pp < 4; pp++) {
        const int p0 = pgrp * 8 + pp * 2;
        float rmax[2][2][4];                   // [pq][it][r], persists across passes
#pragma unroll
        for (int pq = 0; pq < 2; pq++)
#pragma unroll
            for (int it = 0; it < 2; it++)
#pragma unroll
                for (int r = 0; r < 4; r++) rmax[pq][it][r] = -INFINITY;

        // ---- 6 uniform 2-tile passes (NOT unrolled: caps live ranges, r12-proven) ----
#pragma unroll 1
        for (int pass = 0; pass < 6; pass++) {
            const int jb0 = pass * 32;
            const int jb1 = jb0 + 16;
            f32x4v acc[2][2][2];               // [pq][it][jt] = 64 acc regs
#pragma unroll
            for (int pq = 0; pq < 2; pq++)
#pragma unroll
                for (int it = 0; it < 2; it++)
#pragma unroll
                    for (int jt = 0; jt < 2; jt++) acc[pq][it][jt] = (f32x4v)0.f;

            f16x8 kq0 = *(const f16x8*)&kqs[quad * 128 + p0 * 8];
            f16x8 kq1 = *(const f16x8*)&kqs[quad * 128 + p0 * 8 + 8];
            f16x8 hb0 = *(const f16x8*)&h2s[(jb0 + c) * PS + quad * 8];
            f16x8 hb1 = *(const f16x8*)&h2s[(jb1 + c) * PS + quad * 8];

#pragma unroll
            for (int ch = 0; ch < NCH; ch++) {
                f16x8 kq0n = kq0, kq1n = kq1, hb0n = hb0, hb1n = hb1;
                if (ch < NCH - 1) {
                    kq0n = *(const f16x8*)&kqs[(ch + 1) * 512 + quad * 128 + p0 * 8];
                    kq1n = *(const f16x8*)&kqs[(ch + 1) * 512 + quad * 128 + p0 * 8 + 8];
                    hb0n = *(const f16x8*)&h2s[(jb0 + c) * PS + (ch + 1) * 32 + quad * 8];
                    hb1n = *(const f16x8*)&h2s[(jb1 + c) * PS + (ch + 1) * 32 + quad * 8];
                }
                f16x8 sa00 = af[0][ch] * kq0;
                f16x8 sa10 = af[1][ch] * kq0;
                f16x8 sa01 = af[0][ch] * kq1;
                f16x8 sa11 = af[1][ch] * kq1;
                acc[0][0][0] = __builtin_amdgcn_mfma_f32_16x16x32_f16(sa00, hb0, acc[0][0][0], 0, 0, 0);
                acc[0][1][0] = __builtin_amdgcn_mfma_f32_16x16x32_f16(sa10, hb0, acc[0][1][0], 0, 0, 0);
                acc[1][0][0] = __builtin_amdgcn_mfma_f32_16x16x32_f16(sa01, hb0, acc[1][0][0], 0, 0, 0);
                acc[1][1][0] = __builtin_amdgcn_mfma_f32_16x16x32_f16(sa11, hb0, acc[1][1][0], 0, 0, 0);
                acc[0][0][1] = __builtin_amdgcn_mfma_f32_16x16x32_f16(sa00, hb1, acc[0][0][1], 0, 0, 0);
                acc[0][1][1] = __builtin_amdgcn_mfma_f32_16x16x32_f16(sa10, hb1, acc[0][1][1], 0, 0, 0);
                acc[1][0][1] = __builtin_amdgcn_mfma_f32_16x16x32_f16(sa01, hb1, acc[1][0][1], 0, 0, 0);
                acc[1][1][1] = __builtin_amdgcn_mfma_f32_16x16x32_f16(sa11, hb1, acc[1][1][1], 0, 0, 0);
                kq0 = kq0n; kq1 = kq1n; hb0 = hb0n; hb1 = hb1n;
            }
#pragma unroll
            for (int pq = 0; pq < 2; pq++) {
                float n20 = (float)n2s[(jb0 + c) * PP + p0 + pq];
                float n21 = (float)n2s[(jb1 + c) * PP + p0 + pq];
#pragma unroll
                for (int it = 0; it < 2; it++)
#pragma unroll
                    for (int r = 0; r < 4; r++) {
                        rmax[pq][it][r] = fmaxf(rmax[pq][it][r], acc[pq][it][0][r] * n20);
                        rmax[pq][it][r] = fmaxf(rmax[pq][it][r], acc[pq][it][1][r] * n21);
                    }
            }
        }

        // ---- peeled final single-tile pass: rows 184..199 (overlap; max idempotent) ----
        {
            const int jb0 = 184;
            f32x4v acc[2][2];                  // [pq][it] = 32 acc regs
#pragma unroll
            for (int pq = 0; pq < 2; pq++)
#pragma unroll
                for (int it = 0; it < 2; it++) acc[pq][it] = (f32x4v)0.f;

            f16x8 kq0 = *(const f16x8*)&kqs[quad * 128 + p0 * 8];
            f16x8 kq1 = *(const f16x8*)&kqs[quad * 128 + p0 * 8 + 8];
            f16x8 hb0 = *(const f16x8*)&h2s[(jb0 + c) * PS + quad * 8];

#pragma unroll
            for (int ch = 0; ch < NCH; ch++) {
                f16x8 kq0n = kq0, kq1n = kq1, hb0n = hb0;
                if (ch < NCH - 1) {
                    kq0n = *(const f16x8*)&kqs[(ch + 1) * 512 + quad * 128 + p0 * 8];
                    kq1n = *(const f16x8*)&kqs[(ch + 1) * 512 + quad * 128 + p0 * 8 + 8];
                    hb0n = *(const f16x8*)&h2s[(jb0 + c) * PS + (ch + 1) * 32 + quad * 8];
                }
                f16x8 sa00 = af[0][ch] * kq0;
                f16x8 sa10 = af[1][ch] * kq0;
                f16x8 sa01 = af[0][ch] * kq1;
                f16x8 sa11 = af[1][ch] * kq1;
                acc[0][0] = __builtin_amdgcn_mfma_f32_16x16x32_f16(sa00, hb0, acc[0][0], 0, 0, 0);
                acc[0][1] = __builtin_amdgcn_mfma_f32_16x16x32_f16(sa10, hb0, acc[0][1], 0, 0, 0);
                acc[1][0] = __builtin_amdgcn_mfma_f32_16x16x32_f16(sa01, hb0, acc[1][0], 0, 0, 0);
                acc[1][1] = __builtin_amdgcn_mfma_f32_16x16x32_f16(sa11, hb0, acc[1][1], 0, 0, 0);
                kq0 = kq0n; kq1 = kq1n; hb0 = hb0n;
            }
#pragma unroll
            for (int pq = 0; pq < 2; pq++) {
                float n20 = (float)n2s[(jb0 + c) * PP + p0 + pq];
#pragma unroll
                for (int it = 0; it < 2; it++)
#pragma unroll
                    for (int r = 0; r < 4; r++)
                        rmax[pq][it][r] = fmaxf(rmax[pq][it][r], acc[pq][it][r] * n20);
            }
        }

        // reduce over j-col (lane bits 0..3), scale by n1inv, write out directly
#pragma unroll
        for (int pq = 0; pq < 2; pq++) {
#pragma unroll
            for (int m = 1; m <= 8; m <<= 1)
#pragma unroll
                for (int it = 0; it < 2; it++)
#pragma unroll
                    for (int r = 0; r < 4; r++)
                        rmax[pq][it][r] = fmaxf(rmax[pq][it][r], __shfl_xor(rmax[pq][it][r], m));
            if (c == 0) {
#pragma unroll
                for (int it = 0; it < 2; it++)
#pragma unroll
                    for (int r = 0; r < 4; r++) {
                        int i = ibase + it * 16 + quad * 4 + r;   // < 200 by construction
                        size_t o = ((size_t)b * LL + i) * PP + p0 + pq;
                        out[o] = rmax[pq][it][r] * n1inv[o];
                    }
            }
        }
    }
}

extern "C" void kernel_launch(void* const* d_in, const int* in_sizes, int n_in,
                              void* d_out, int out_size, void* d_ws, size_t ws_size,
                              hipStream_t stream) {
    const float* sent1  = (const float*)d_in[0];   // (64,200,300) f32
    const float* sent2  = (const float*)d_in[1];   // (64,200,300) f32
    const float* kernel = (const float*)d_in[2];   // (16,300)     f32
    float* out = (float*)d_out;                    // (64,200,16)  f32

    char* ws = (char*)d_ws;
    float*    n1inv = (float*)ws;                  ws += (size_t)BBATCH * LL * PP * 4;   // 0.82 MB
    _Float16* n2inv = (_Float16*)ws;               ws += (size_t)BBATCH * LL * PP * 2;   // 0.41 MB
    _Float16* h1    = (_Float16*)ws;               ws += (size_t)BBATCH * LL * KG * 2;   // 8.19 MB
    _Float16* h2    = (_Float16*)ws;               ws += (size_t)BBATCH * LL * KG * 2;   // 8.19 MB
    _Float16* ksqt  = (_Float16*)ws;               // 10 KB (total ~17.6 MB)

    ksq_kernel<<<1, 256, 0, stream>>>(kernel, ksqt);

    prep_kernel<<<dim3(7, 2, BBATCH), 256, 0, stream>>>(sent1, sent2,
                                                        n1inv, n2inv, h1, h2, ksqt);

    const int lds_bytes = (200 * PS + 200 * PP + 5120) * 2;   // 147,840 B -> 1 block/CU
    hipFuncSetAttribute((const void*)maxsim_kernel,
                        hipFuncAttributeMaxDynamicSharedMemorySize, lds_bytes);
    maxsim_kernel<<<dim3(256, 1, 1), 256, lds_bytes, stream>>>(h1, h2, ksqt, n2inv, n1inv, out);
}

// Round 14
// 126.682 us; speedup vs baseline: 1.0128x; 1.0128x over previous
//
#include <hip/hip_runtime.h>
#include <math.h>

#define BBATCH 64
#define LL 200
#define DD 300
#define PP 16
#define EPSV 1e-12f
#define KG 320          // global K-pad (10 chunks of 32)
#define PS 328          // maxsim B-tile LDS row stride in halfs (conflict-free for b128: 4(c+quad) covers all 32 banks)
#define NCH 10
#define KQS 136         // kqs quad stride in halfs: 272 B -> bank = 4*quad + 4*p (4 distinct groups; was 256 B = same group 4-way)
#define N2S 24          // n2s row stride in halfs: 48 B -> bank = 12c mod 32 (2-way, free; was 32 B = 16-way), 16B-aligned

typedef _Float16 f16x8 __attribute__((ext_vector_type(8)));
typedef float f32x4v __attribute__((ext_vector_type(4)));

// ---------------- ksq: one-block micro-kernel builds the k^2 frag table -----------------
// (UNCHANGED from r13.)
__global__ __launch_bounds__(256) void ksq_kernel(const float* __restrict__ kern,
                                                  _Float16* __restrict__ ksqt) {
    __shared__ float kl[16][320];   // 20.5 KB, cols 300..319 zeroed
    const int t = threadIdx.x;
    for (int idx = t; idx < 16 * 75; idx += 256) {
        int p = idx / 75, c4 = (idx - p * 75) * 4;
        *(float4*)&kl[p][c4] = *(const float4*)&kern[p * DD + c4];
    }
    for (int idx = t; idx < 16 * 20; idx += 256) {
        int p = idx / 20, cc = 300 + (idx - p * 20);
        kl[p][cc] = 0.f;
    }
    __syncthreads();
    for (int ent = t; ent < 640; ent += 256) {
        int ch = ent >> 6, rem = ent & 63;
        int quad = rem >> 4, p = rem & 15;
        int k0 = ch * 32 + quad * 8;
        float4 a = *(const float4*)&kl[p][k0];
        float4 d = *(const float4*)&kl[p][k0 + 4];
        f16x8 h;
        h[0] = (_Float16)(a.x * a.x); h[1] = (_Float16)(a.y * a.y);
        h[2] = (_Float16)(a.z * a.z); h[3] = (_Float16)(a.w * a.w);
        h[4] = (_Float16)(d.x * d.x); h[5] = (_Float16)(d.y * d.y);
        h[6] = (_Float16)(d.z * d.z); h[7] = (_Float16)(d.w * d.w);
        *(f16x8*)&ksqt[(size_t)ent * 8] = h;
    }
}

// ---------------- prep: ZERO-LDS emit-during-staging + MFMA norms ------------------------
// (UNCHANGED from r13.)
__global__ __launch_bounds__(256) void prep_kernel(const float* __restrict__ s1,
                                                   const float* __restrict__ s2,
                                                   float* __restrict__ n1inv,
                                                   _Float16* __restrict__ n2inv,
                                                   _Float16* __restrict__ h1,
                                                   _Float16* __restrict__ h2,
                                                   const _Float16* __restrict__ ksqt) {
    const int grp   = blockIdx.x;   // 0..6 (32-row groups)
    const int which = blockIdx.y;
    const int b     = blockIdx.z;
    const float* s  = which ? s2 : s1;
    _Float16* hout  = which ? h2 : h1;
    const int r0    = grp * 32;
    const int t     = threadIdx.x;

    for (int idx = t; idx < 32 * 40; idx += 256) {
        int r = idx / 40, q = idx - r * 40;
        int row = r0 + r;
        if (row >= LL) continue;
        int q8 = q * 8;
        const float* src = &s[((size_t)b * LL + row) * DD];
        f16x8 h;
        if (q8 + 8 <= DD) {
            float4 a = *(const float4*)&src[q8];
            float4 d = *(const float4*)&src[q8 + 4];
            h[0] = (_Float16)a.x; h[1] = (_Float16)a.y; h[2] = (_Float16)a.z; h[3] = (_Float16)a.w;
            h[4] = (_Float16)d.x; h[5] = (_Float16)d.y; h[6] = (_Float16)d.z; h[7] = (_Float16)d.w;
        } else if (q8 < DD) {
            float4 a = *(const float4*)&src[q8];
            h[0] = (_Float16)a.x; h[1] = (_Float16)a.y; h[2] = (_Float16)a.z; h[3] = (_Float16)a.w;
            h[4] = (_Float16)0.f; h[5] = (_Float16)0.f; h[6] = (_Float16)0.f; h[7] = (_Float16)0.f;
        } else {
#pragma unroll
            for (int e = 0; e < 8; e++) h[e] = (_Float16)0.f;
        }
        *(f16x8*)&hout[((size_t)b * LL + row) * KG + q8] = h;
    }
    __syncthreads();   // drains vmcnt(0): h writes visible block-wide

    const int lane = t & 63;
    const int w    = t >> 6;
    if (w < 2) {
        const int rg   = w;
        const int c    = lane & 15;
        const int quad = lane >> 4;
        int arow = r0 + rg * 16 + c;
        int rowc = arow < LL ? arow : LL - 1;
        const _Float16* hb = &hout[((size_t)b * LL + rowc) * KG];
        f32x4v nacc = (f32x4v)0.f;
#pragma unroll
        for (int ch = 0; ch < NCH; ch++) {
            f16x8 av = *(const f16x8*)&hb[ch * 32 + quad * 8];
            f16x8 sa = av * av;
            f16x8 bk = *(const f16x8*)&ksqt[((size_t)(ch * 4 + quad) * 16 + c) * 8];
            nacc = __builtin_amdgcn_mfma_f32_16x16x32_f16(sa, bk, nacc, 0, 0, 0);
        }
#pragma unroll
        for (int r = 0; r < 4; r++) {
            int row = r0 + rg * 16 + quad * 4 + r;
            if (row < LL) {
                float inv = 1.0f / sqrtf(fmaxf(nacc[r], EPSV));
                if (which) n2inv[((size_t)b * LL + row) * PP + c] = (_Float16)inv;
                else       n1inv[((size_t)b * LL + row) * PP + c] = inv;
            }
        }
    }
}

// ---------------- maxsim: full-j + bank-conflict pads + distance-2 LDS pipeline ----------
// r13 counters: SQ_LDS_BANK_CONFLICT 2.98M. Bank math: h2s b128 reads are already optimal
// (4(c+quad) covers all 32 banks); the offenders were kqs (quad stride 256 B == same 4-bank
// group -> 4-way, ~1.7M) and n2s (row stride 32 B -> 16 lanes/bank, ~0.7M). Fixed via KQS=136
// / N2S=24 pad strides. Also distance-2 prefetch (3-slot named rotation, +~32 regs, ~220
// total, no spill at (256,1)): LDS-pipe queueing inflates return latency past distance-1's
// ~150-cyc slack. LDS 151.7 KB -> 1 block/CU (unchanged).
__global__ __launch_bounds__(256, 1) void maxsim_kernel(const _Float16* __restrict__ h1,
                                                        const _Float16* __restrict__ h2,
                                                        const _Float16* __restrict__ ksqt,
                                                        const _Float16* __restrict__ n2inv,
                                                        const float* __restrict__ n1inv,
                                                        float* __restrict__ out) {
    extern __shared__ __align__(16) char smem[];
    _Float16* h2s = (_Float16*)smem;          // 200*PS halfs        = 131,200 B
    _Float16* n2s = h2s + 200 * PS;           // 200*N2S halfs       =   9,600 B
    _Float16* kqs = n2s + 200 * N2S;          // 10*4*KQS halfs      =  10,880 B (total 151,680)

    const int blk  = blockIdx.x;
    const int b    = blk & 63;
    const int v    = blk >> 6;                // 0..3
    const int iblk = v & 1;
    const int pgrp = v >> 1;
    const int i0   = iblk ? 72 : 0;
    const int t    = threadIdx.x;

    const int lane = t & 63;
    const int w    = t >> 6;                  // 4 waves
    const int c    = lane & 15;
    const int quad = lane >> 4;
    const int ibase = i0 + w * 32;

    // A fragments: global -> registers (20 x b128 = 80 VGPR; h1 is L2/L3-hot)
    f16x8 af[2][NCH];
    {
        const _Float16* g1 = h1 + (size_t)b * LL * KG;
#pragma unroll
        for (int it = 0; it < 2; it++)
#pragma unroll
            for (int ch = 0; ch < NCH; ch++)
                af[it][ch] = *(const f16x8*)&g1[(size_t)(ibase + it * 16 + c) * KG + ch * 32 + quad * 8];
    }

    // stage FULL B tile (200 rows) + n2 (padded stride) + ksq table (padded quad stride)
    {
        const _Float16* g2 = h2 + (size_t)b * LL * KG;
        for (int idx = t; idx < 200 * 40; idx += 256) {
            int r = idx / 40, q = idx - r * 40;
            *(f16x8*)&h2s[r * PS + q * 8] = *(const f16x8*)&g2[(size_t)idx * 8];
        }
        const _Float16* gn = n2inv + (size_t)b * LL * PP;
        for (int idx = t; idx < 400; idx += 256)   // unit = 8 halfs; row = idx>>1, half u = idx&1
            *(f16x8*)&n2s[(idx >> 1) * N2S + (idx & 1) * 8] = *(const f16x8*)&gn[(size_t)idx * 8];
        for (int ent = t; ent < 640; ent += 256) { // ent = (ch*4+quad)*16+p
            int ch = ent >> 6, rem = ent & 63;
            int qd = rem >> 4, p = rem & 15;
            *(f16x8*)&kqs[ch * (4 * KQS) + qd * KQS + p * 8] = *(const f16x8*)&ksqt[(size_t)ent * 8];
        }
    }
    __syncthreads();

    const int kqb = quad * KQS;               // lane's quad base within a ch-block

    for (int pp = 0; pp < 4; pp++) {
        const int p0 = pgrp * 8 + pp * 2;
        float rmax[2][2][4];                   // [pq][it][r], persists across passes
#pragma unroll
        for (int pq = 0; pq < 2; pq++)
#pragma unroll
            for (int it = 0; it < 2; it++)
#pragma unroll
                for (int r = 0; r < 4; r++) rmax[pq][it][r] = -INFINITY;

#define LQ0(CH) (*(const f16x8*)&kqs[(CH) * (4 * KQS) + kqb + p0 * 8])
#define LQ1(CH) (*(const f16x8*)&kqs[(CH) * (4 * KQS) + kqb + p0 * 8 + 8])
#define LH(JB, CH) (*(const f16x8*)&h2s[((JB) + c) * PS + (CH) * 32 + quad * 8])

        // ---- 6 uniform 2-tile passes (NOT unrolled: caps live ranges, r12-proven) ----
#pragma unroll 1
        for (int pass = 0; pass < 6; pass++) {
            const int jb0 = pass * 32;
            const int jb1 = jb0 + 16;
            f32x4v acc[2][2][2];               // [pq][it][jt] = 64 acc regs
#pragma unroll
            for (int pq = 0; pq < 2; pq++)
#pragma unroll
                for (int it = 0; it < 2; it++)
#pragma unroll
                    for (int jt = 0; jt < 2; jt++) acc[pq][it][jt] = (f32x4v)0.f;

            // distance-2 prefetch: slots a = ch, b = ch+1, c(new) = ch+2
            f16x8 kq0a = LQ0(0), kq1a = LQ1(0), hb0a = LH(jb0, 0), hb1a = LH(jb1, 0);
            f16x8 kq0b = LQ0(1), kq1b = LQ1(1), hb0b = LH(jb0, 1), hb1b = LH(jb1, 1);

#pragma unroll
            for (int ch = 0; ch < NCH; ch++) {
                f16x8 kq0c = kq0b, kq1c = kq1b, hb0c = hb0b, hb1c = hb1b;
                if (ch < NCH - 2) {
                    kq0c = LQ0(ch + 2); kq1c = LQ1(ch + 2);
                    hb0c = LH(jb0, ch + 2); hb1c = LH(jb1, ch + 2);
                }
                f16x8 sa00 = af[0][ch] * kq0a;
                f16x8 sa10 = af[1][ch] * kq0a;
                f16x8 sa01 = af[0][ch] * kq1a;
                f16x8 sa11 = af[1][ch] * kq1a;
                acc[0][0][0] = __builtin_amdgcn_mfma_f32_16x16x32_f16(sa00, hb0a, acc[0][0][0], 0, 0, 0);
                acc[0][1][0] = __builtin_amdgcn_mfma_f32_16x16x32_f16(sa10, hb0a, acc[0][1][0], 0, 0, 0);
                acc[1][0][0] = __builtin_amdgcn_mfma_f32_16x16x32_f16(sa01, hb0a, acc[1][0][0], 0, 0, 0);
                acc[1][1][0] = __builtin_amdgcn_mfma_f32_16x16x32_f16(sa11, hb0a, acc[1][1][0], 0, 0, 0);
                acc[0][0][1] = __builtin_amdgcn_mfma_f32_16x16x32_f16(sa00, hb1a, acc[0][0][1], 0, 0, 0);
                acc[0][1][1] = __builtin_amdgcn_mfma_f32_16x16x32_f16(sa10, hb1a, acc[0][1][1], 0, 0, 0);
                acc[1][0][1] = __builtin_amdgcn_mfma_f32_16x16x32_f16(sa01, hb1a, acc[1][0][1], 0, 0, 0);
                acc[1][1][1] = __builtin_amdgcn_mfma_f32_16x16x32_f16(sa11, hb1a, acc[1][1][1], 0, 0, 0);
                kq0a = kq0b; kq1a = kq1b; hb0a = hb0b; hb1a = hb1b;
                kq0b = kq0c; kq1b = kq1c; hb0b = hb0c; hb1b = hb1c;
            }
#pragma unroll
            for (int pq = 0; pq < 2; pq++) {
                float n20 = (float)n2s[(jb0 + c) * N2S + p0 + pq];
                float n21 = (float)n2s[(jb1 + c) * N2S + p0 + pq];
#pragma unroll
                for (int it = 0; it < 2; it++)
#pragma unroll
                    for (int r = 0; r < 4; r++) {
                        rmax[pq][it][r] = fmaxf(rmax[pq][it][r], acc[pq][it][0][r] * n20);
                        rmax[pq][it][r] = fmaxf(rmax[pq][it][r], acc[pq][it][1][r] * n21);
                    }
            }
        }

        // ---- peeled final single-tile pass: rows 184..199 (overlap; max idempotent) ----
        {
            const int jb0 = 184;
            f32x4v acc[2][2];                  // [pq][it] = 32 acc regs
#pragma unroll
            for (int pq = 0; pq < 2; pq++)
#pragma unroll
                for (int it = 0; it < 2; it++) acc[pq][it] = (f32x4v)0.f;

            f16x8 kq0a = LQ0(0), kq1a = LQ1(0), hb0a = LH(jb0, 0);
            f16x8 kq0b = LQ0(1), kq1b = LQ1(1), hb0b = LH(jb0, 1);

#pragma unroll
            for (int ch = 0; ch < NCH; ch++) {
                f16x8 kq0c = kq0b, kq1c = kq1b, hb0c = hb0b;
                if (ch < NCH - 2) {
                    kq0c = LQ0(ch + 2); kq1c = LQ1(ch + 2);
                    hb0c = LH(jb0, ch + 2);
                }
                f16x8 sa00 = af[0][ch] * kq0a;
                f16x8 sa10 = af[1][ch] * kq0a;
                f16x8 sa01 = af[0][ch] * kq1a;
                f16x8 sa11 = af[1][ch] * kq1a;
                acc[0][0] = __builtin_amdgcn_mfma_f32_16x16x32_f16(sa00, hb0a, acc[0][0], 0, 0, 0);
                acc[0][1] = __builtin_amdgcn_mfma_f32_16x16x32_f16(sa10, hb0a, acc[0][1], 0, 0, 0);
                acc[1][0] = __builtin_amdgcn_mfma_f32_16x16x32_f16(sa01, hb0a, acc[1][0], 0, 0, 0);
                acc[1][1] = __builtin_amdgcn_mfma_f32_16x16x32_f16(sa11, hb0a, acc[1][1], 0, 0, 0);
                kq0a = kq0b; kq1a = kq1b; hb0a = hb0b;
                kq0b = kq0c; kq1b = kq1c; hb0b = hb0c;
            }
#pragma unroll
            for (int pq = 0; pq < 2; pq++) {
                float n20 = (float)n2s[(jb0 + c) * N2S + p0 + pq];
#pragma unroll
                for (int it = 0; it < 2; it++)
#pragma unroll
                    for (int r = 0; r < 4; r++)
                        rmax[pq][it][r] = fmaxf(rmax[pq][it][r], acc[pq][it][r] * n20);
            }
        }
#undef LQ0
#undef LQ1
#undef LH

        // reduce over j-col (lane bits 0..3), scale by n1inv, write out directly
#pragma unroll
        for (int pq = 0; pq < 2; pq++) {
#pragma unroll
            for (int m = 1; m <= 8; m <<= 1)
#pragma unroll
                for (int it = 0; it < 2; it++)
#pragma unroll
                    for (int r = 0; r < 4; r++)
                        rmax[pq][it][r] = fmaxf(rmax[pq][it][r], __shfl_xor(rmax[pq][it][r], m));
            if (c == 0) {
#pragma unroll
                for (int it = 0; it < 2; it++)
#pragma unroll
                    for (int r = 0; r < 4; r++) {
                        int i = ibase + it * 16 + quad * 4 + r;   // < 200 by construction
                        size_t o = ((size_t)b * LL + i) * PP + p0 + pq;
                        out[o] = rmax[pq][it][r] * n1inv[o];
                    }
            }
        }
    }
}

extern "C" void kernel_launch(void* const* d_in, const int* in_sizes, int n_in,
                              void* d_out, int out_size, void* d_ws, size_t ws_size,
                              hipStream_t stream) {
    const float* sent1  = (const float*)d_in[0];   // (64,200,300) f32
    const float* sent2  = (const float*)d_in[1];   // (64,200,300) f32
    const float* kernel = (const float*)d_in[2];   // (16,300)     f32
    float* out = (float*)d_out;                    // (64,200,16)  f32

    char* ws = (char*)d_ws;
    float*    n1inv = (float*)ws;                  ws += (size_t)BBATCH * LL * PP * 4;   // 0.82 MB
    _Float16* n2inv = (_Float16*)ws;               ws += (size_t)BBATCH * LL * PP * 2;   // 0.41 MB
    _Float16* h1    = (_Float16*)ws;               ws += (size_t)BBATCH * LL * KG * 2;   // 8.19 MB
    _Float16* h2    = (_Float16*)ws;               ws += (size_t)BBATCH * LL * KG * 2;   // 8.19 MB
    _Float16* ksqt  = (_Float16*)ws;               // 10 KB (total ~17.6 MB)

    ksq_kernel<<<1, 256, 0, stream>>>(kernel, ksqt);

    prep_kernel<<<dim3(7, 2, BBATCH), 256, 0, stream>>>(sent1, sent2,
                                                        n1inv, n2inv, h1, h2, ksqt);

    const int lds_bytes = (200 * PS + 200 * N2S + 10 * 4 * KQS) * 2;   // 151,680 B -> 1 block/CU
    hipFuncSetAttribute((const void*)maxsim_kernel,
                        hipFuncAttributeMaxDynamicSharedMemorySize, lds_bytes);
    maxsim_kernel<<<dim3(256, 1, 1), 256, lds_bytes, stream>>>(h1, h2, ksqt, n2inv, n1inv, out);
}

// Round 15
// 124.216 us; speedup vs baseline: 1.0329x; 1.0199x over previous
//
#include <hip/hip_runtime.h>
#include <math.h>

#define BBATCH 64
#define LL 200
#define DD 300
#define PP 16
#define EPSV 1e-12f
#define KG 320          // global K-pad (10 chunks of 32)
#define PS 328          // maxsim B-tile LDS row stride in halfs (conflict-free for b128: 4(c+quad) covers all 32 banks)
#define NCH 10
#define KQS 136         // kqs quad stride in halfs: 272 B -> bank = 4*quad (4 distinct groups)
#define N2S 24          // n2s row stride in halfs: 48 B -> bank = 12c mod 32 (2-way, free), 16B-aligned

typedef _Float16 f16x8 __attribute__((ext_vector_type(8)));
typedef float f32x4v __attribute__((ext_vector_type(4)));

// ---------------- ksq: one-block micro-kernel builds the k^2 frag table -----------------
// (UNCHANGED from r13.)
__global__ __launch_bounds__(256) void ksq_kernel(const float* __restrict__ kern,
                                                  _Float16* __restrict__ ksqt) {
    __shared__ float kl[16][320];   // 20.5 KB, cols 300..319 zeroed
    const int t = threadIdx.x;
    for (int idx = t; idx < 16 * 75; idx += 256) {
        int p = idx / 75, c4 = (idx - p * 75) * 4;
        *(float4*)&kl[p][c4] = *(const float4*)&kern[p * DD + c4];
    }
    for (int idx = t; idx < 16 * 20; idx += 256) {
        int p = idx / 20, cc = 300 + (idx - p * 20);
        kl[p][cc] = 0.f;
    }
    __syncthreads();
    for (int ent = t; ent < 640; ent += 256) {
        int ch = ent >> 6, rem = ent & 63;
        int quad = rem >> 4, p = rem & 15;
        int k0 = ch * 32 + quad * 8;
        float4 a = *(const float4*)&kl[p][k0];
        float4 d = *(const float4*)&kl[p][k0 + 4];
        f16x8 h;
        h[0] = (_Float16)(a.x * a.x); h[1] = (_Float16)(a.y * a.y);
        h[2] = (_Float16)(a.z * a.z); h[3] = (_Float16)(a.w * a.w);
        h[4] = (_Float16)(d.x * d.x); h[5] = (_Float16)(d.y * d.y);
        h[6] = (_Float16)(d.z * d.z); h[7] = (_Float16)(d.w * d.w);
        *(f16x8*)&ksqt[(size_t)ent * 8] = h;
    }
}

// ---------------- prep: ZERO-LDS emit-during-staging + MFMA norms ------------------------
// (UNCHANGED from r13.)
__global__ __launch_bounds__(256) void prep_kernel(const float* __restrict__ s1,
                                                   const float* __restrict__ s2,
                                                   float* __restrict__ n1inv,
                                                   _Float16* __restrict__ n2inv,
                                                   _Float16* __restrict__ h1,
                                                   _Float16* __restrict__ h2,
                                                   const _Float16* __restrict__ ksqt) {
    const int grp   = blockIdx.x;   // 0..6 (32-row groups)
    const int which = blockIdx.y;
    const int b     = blockIdx.z;
    const float* s  = which ? s2 : s1;
    _Float16* hout  = which ? h2 : h1;
    const int r0    = grp * 32;
    const int t     = threadIdx.x;

    for (int idx = t; idx < 32 * 40; idx += 256) {
        int r = idx / 40, q = idx - r * 40;
        int row = r0 + r;
        if (row >= LL) continue;
        int q8 = q * 8;
        const float* src = &s[((size_t)b * LL + row) * DD];
        f16x8 h;
        if (q8 + 8 <= DD) {
            float4 a = *(const float4*)&src[q8];
            float4 d = *(const float4*)&src[q8 + 4];
            h[0] = (_Float16)a.x; h[1] = (_Float16)a.y; h[2] = (_Float16)a.z; h[3] = (_Float16)a.w;
            h[4] = (_Float16)d.x; h[5] = (_Float16)d.y; h[6] = (_Float16)d.z; h[7] = (_Float16)d.w;
        } else if (q8 < DD) {
            float4 a = *(const float4*)&src[q8];
            h[0] = (_Float16)a.x; h[1] = (_Float16)a.y; h[2] = (_Float16)a.z; h[3] = (_Float16)a.w;
            h[4] = (_Float16)0.f; h[5] = (_Float16)0.f; h[6] = (_Float16)0.f; h[7] = (_Float16)0.f;
        } else {
#pragma unroll
            for (int e = 0; e < 8; e++) h[e] = (_Float16)0.f;
        }
        *(f16x8*)&hout[((size_t)b * LL + row) * KG + q8] = h;
    }
    __syncthreads();   // drains vmcnt(0): h writes visible block-wide

    const int lane = t & 63;
    const int w    = t >> 6;
    if (w < 2) {
        const int rg   = w;
        const int c    = lane & 15;
        const int quad = lane >> 4;
        int arow = r0 + rg * 16 + c;
        int rowc = arow < LL ? arow : LL - 1;
        const _Float16* hb = &hout[((size_t)b * LL + rowc) * KG];
        f32x4v nacc = (f32x4v)0.f;
#pragma unroll
        for (int ch = 0; ch < NCH; ch++) {
            f16x8 av = *(const f16x8*)&hb[ch * 32 + quad * 8];
            f16x8 sa = av * av;
            f16x8 bk = *(const f16x8*)&ksqt[((size_t)(ch * 4 + quad) * 16 + c) * 8];
            nacc = __builtin_amdgcn_mfma_f32_16x16x32_f16(sa, bk, nacc, 0, 0, 0);
        }
#pragma unroll
        for (int r = 0; r < 4; r++) {
            int row = r0 + rg * 16 + quad * 4 + r;
            if (row < LL) {
                float inv = 1.0f / sqrtf(fmaxf(nacc[r], EPSV));
                if (which) n2inv[((size_t)b * LL + row) * PP + c] = (_Float16)inv;
                else       n1inv[((size_t)b * LL + row) * PP + c] = inv;
            }
        }
    }
}

// ---------------- maxsim: full-j + kq REGISTER-HOISTED per pp ----------------------------
// r14 pipe model: LDS BW is the wall (4 waves share 1 pipe; ~5200 b128/CU ~ 22 us floor
// vs 4.2 us MFMA). kq is PASS-INVARIANT but was re-read every pass (560 b128/wave).
// Hoist kqr[10][2] (80 VGPR) once per pp: kq LDS reads 560 -> 80 per wave; total LDS
// traffic 5200 -> ~3300 b128/CU (floor ~14 us). Arch regs ~230 <= 256 (acc 64 in AGPR
// half); spill tripwire = FETCH_SIZE (8.7 MB clean). hb keeps distance-2 rotation.
// Bank pads (KQS/N2S) and everything else unchanged from r14.
__global__ __launch_bounds__(256, 1) void maxsim_kernel(const _Float16* __restrict__ h1,
                                                        const _Float16* __restrict__ h2,
                                                        const _Float16* __restrict__ ksqt,
                                                        const _Float16* __restrict__ n2inv,
                                                        const float* __restrict__ n1inv,
                                                        float* __restrict__ out) {
    extern __shared__ __align__(16) char smem[];
    _Float16* h2s = (_Float16*)smem;          // 200*PS halfs        = 131,200 B
    _Float16* n2s = h2s + 200 * PS;           // 200*N2S halfs       =   9,600 B
    _Float16* kqs = n2s + 200 * N2S;          // 10*4*KQS halfs      =  10,880 B (total 151,680)

    const int blk  = blockIdx.x;
    const int b    = blk & 63;
    const int v    = blk >> 6;                // 0..3
    const int iblk = v & 1;
    const int pgrp = v >> 1;
    const int i0   = iblk ? 72 : 0;
    const int t    = threadIdx.x;

    const int lane = t & 63;
    const int w    = t >> 6;                  // 4 waves
    const int c    = lane & 15;
    const int quad = lane >> 4;
    const int ibase = i0 + w * 32;

    // A fragments: global -> registers (20 x b128 = 80 VGPR; h1 is L2/L3-hot)
    f16x8 af[2][NCH];
    {
        const _Float16* g1 = h1 + (size_t)b * LL * KG;
#pragma unroll
        for (int it = 0; it < 2; it++)
#pragma unroll
            for (int ch = 0; ch < NCH; ch++)
                af[it][ch] = *(const f16x8*)&g1[(size_t)(ibase + it * 16 + c) * KG + ch * 32 + quad * 8];
    }

    // stage FULL B tile (200 rows) + n2 (padded stride) + ksq table (padded quad stride)
    {
        const _Float16* g2 = h2 + (size_t)b * LL * KG;
        for (int idx = t; idx < 200 * 40; idx += 256) {
            int r = idx / 40, q = idx - r * 40;
            *(f16x8*)&h2s[r * PS + q * 8] = *(const f16x8*)&g2[(size_t)idx * 8];
        }
        const _Float16* gn = n2inv + (size_t)b * LL * PP;
        for (int idx = t; idx < 400; idx += 256)
            *(f16x8*)&n2s[(idx >> 1) * N2S + (idx & 1) * 8] = *(const f16x8*)&gn[(size_t)idx * 8];
        for (int ent = t; ent < 640; ent += 256) { // ent = (ch*4+quad)*16+p
            int ch = ent >> 6, rem = ent & 63;
            int qd = rem >> 4, p = rem & 15;
            *(f16x8*)&kqs[ch * (4 * KQS) + qd * KQS + p * 8] = *(const f16x8*)&ksqt[(size_t)ent * 8];
        }
    }
    __syncthreads();

    const int kqb = quad * KQS;               // lane's quad base within a ch-block

    for (int pp = 0; pp < 4; pp++) {
        const int p0 = pgrp * 8 + pp * 2;

        // kq register hoist: pass-invariant, 20 b128 LDS reads ONCE per pp (80 VGPR)
        f16x8 kqr[NCH][2];
#pragma unroll
        for (int ch = 0; ch < NCH; ch++) {
            kqr[ch][0] = *(const f16x8*)&kqs[ch * (4 * KQS) + kqb + p0 * 8];
            kqr[ch][1] = *(const f16x8*)&kqs[ch * (4 * KQS) + kqb + p0 * 8 + 8];
        }

        float rmax[2][2][4];                   // [pq][it][r], persists across passes
#pragma unroll
        for (int pq = 0; pq < 2; pq++)
#pragma unroll
            for (int it = 0; it < 2; it++)
#pragma unroll
                for (int r = 0; r < 4; r++) rmax[pq][it][r] = -INFINITY;

#define LH(JB, CH) (*(const f16x8*)&h2s[((JB) + c) * PS + (CH) * 32 + quad * 8])

        // ---- 6 uniform 2-tile passes (NOT unrolled: caps live ranges, r12-proven) ----
#pragma unroll 1
        for (int pass = 0; pass < 6; pass++) {
            const int jb0 = pass * 32;
            const int jb1 = jb0 + 16;
            f32x4v acc[2][2][2];               // [pq][it][jt] = 64 acc regs
#pragma unroll
            for (int pq = 0; pq < 2; pq++)
#pragma unroll
                for (int it = 0; it < 2; it++)
#pragma unroll
                    for (int jt = 0; jt < 2; jt++) acc[pq][it][jt] = (f32x4v)0.f;

            // distance-2 hb prefetch: slots a = ch, b = ch+1, c(new) = ch+2
            f16x8 hb0a = LH(jb0, 0), hb1a = LH(jb1, 0);
            f16x8 hb0b = LH(jb0, 1), hb1b = LH(jb1, 1);

#pragma unroll
            for (int ch = 0; ch < NCH; ch++) {
                f16x8 hb0c = hb0b, hb1c = hb1b;
                if (ch < NCH - 2) {
                    hb0c = LH(jb0, ch + 2); hb1c = LH(jb1, ch + 2);
                }
                f16x8 sa00 = af[0][ch] * kqr[ch][0];
                f16x8 sa10 = af[1][ch] * kqr[ch][0];
                f16x8 sa01 = af[0][ch] * kqr[ch][1];
                f16x8 sa11 = af[1][ch] * kqr[ch][1];
                acc[0][0][0] = __builtin_amdgcn_mfma_f32_16x16x32_f16(sa00, hb0a, acc[0][0][0], 0, 0, 0);
                acc[0][1][0] = __builtin_amdgcn_mfma_f32_16x16x32_f16(sa10, hb0a, acc[0][1][0], 0, 0, 0);
                acc[1][0][0] = __builtin_amdgcn_mfma_f32_16x16x32_f16(sa01, hb0a, acc[1][0][0], 0, 0, 0);
                acc[1][1][0] = __builtin_amdgcn_mfma_f32_16x16x32_f16(sa11, hb0a, acc[1][1][0], 0, 0, 0);
                acc[0][0][1] = __builtin_amdgcn_mfma_f32_16x16x32_f16(sa00, hb1a, acc[0][0][1], 0, 0, 0);
                acc[0][1][1] = __builtin_amdgcn_mfma_f32_16x16x32_f16(sa10, hb1a, acc[0][1][1], 0, 0, 0);
                acc[1][0][1] = __builtin_amdgcn_mfma_f32_16x16x32_f16(sa01, hb1a, acc[1][0][1], 0, 0, 0);
                acc[1][1][1] = __builtin_amdgcn_mfma_f32_16x16x32_f16(sa11, hb1a, acc[1][1][1], 0, 0, 0);
                hb0a = hb0b; hb1a = hb1b;
                hb0b = hb0c; hb1b = hb1c;
            }
#pragma unroll
            for (int pq = 0; pq < 2; pq++) {
                float n20 = (float)n2s[(jb0 + c) * N2S + p0 + pq];
                float n21 = (float)n2s[(jb1 + c) * N2S + p0 + pq];
#pragma unroll
                for (int it = 0; it < 2; it++)
#pragma unroll
                    for (int r = 0; r < 4; r++) {
                        rmax[pq][it][r] = fmaxf(rmax[pq][it][r], acc[pq][it][0][r] * n20);
                        rmax[pq][it][r] = fmaxf(rmax[pq][it][r], acc[pq][it][1][r] * n21);
                    }
            }
        }

        // ---- peeled final single-tile pass: rows 184..199 (overlap; max idempotent) ----
        {
            const int jb0 = 184;
            f32x4v acc[2][2];                  // [pq][it] = 32 acc regs
#pragma unroll
            for (int pq = 0; pq < 2; pq++)
#pragma unroll
                for (int it = 0; it < 2; it++) acc[pq][it] = (f32x4v)0.f;

            f16x8 hb0a = LH(jb0, 0);
            f16x8 hb0b = LH(jb0, 1);

#pragma unroll
            for (int ch = 0; ch < NCH; ch++) {
                f16x8 hb0c = hb0b;
                if (ch < NCH - 2) hb0c = LH(jb0, ch + 2);
                f16x8 sa00 = af[0][ch] * kqr[ch][0];
                f16x8 sa10 = af[1][ch] * kqr[ch][0];
                f16x8 sa01 = af[0][ch] * kqr[ch][1];
                f16x8 sa11 = af[1][ch] * kqr[ch][1];
                acc[0][0] = __builtin_amdgcn_mfma_f32_16x16x32_f16(sa00, hb0a, acc[0][0], 0, 0, 0);
                acc[0][1] = __builtin_amdgcn_mfma_f32_16x16x32_f16(sa10, hb0a, acc[0][1], 0, 0, 0);
                acc[1][0] = __builtin_amdgcn_mfma_f32_16x16x32_f16(sa01, hb0a, acc[1][0], 0, 0, 0);
                acc[1][1] = __builtin_amdgcn_mfma_f32_16x16x32_f16(sa11, hb0a, acc[1][1], 0, 0, 0);
                hb0a = hb0b; hb0b = hb0c;
            }
#pragma unroll
            for (int pq = 0; pq < 2; pq++) {
                float n20 = (float)n2s[(jb0 + c) * N2S + p0 + pq];
#pragma unroll
                for (int it = 0; it < 2; it++)
#pragma unroll
                    for (int r = 0; r < 4; r++)
                        rmax[pq][it][r] = fmaxf(rmax[pq][it][r], acc[pq][it][r] * n20);
            }
        }
#undef LH

        // reduce over j-col (lane bits 0..3), scale by n1inv, write out directly
#pragma unroll
        for (int pq = 0; pq < 2; pq++) {
#pragma unroll
            for (int m = 1; m <= 8; m <<= 1)
#pragma unroll
                for (int it = 0; it < 2; it++)
#pragma unroll
                    for (int r = 0; r < 4; r++)
                        rmax[pq][it][r] = fmaxf(rmax[pq][it][r], __shfl_xor(rmax[pq][it][r], m));
            if (c == 0) {
#pragma unroll
                for (int it = 0; it < 2; it++)
#pragma unroll
                    for (int r = 0; r < 4; r++) {
                        int i = ibase + it * 16 + quad * 4 + r;   // < 200 by construction
                        size_t o = ((size_t)b * LL + i) * PP + p0 + pq;
                        out[o] = rmax[pq][it][r] * n1inv[o];
                    }
            }
        }
    }
}

extern "C" void kernel_launch(void* const* d_in, const int* in_sizes, int n_in,
                              void* d_out, int out_size, void* d_ws, size_t ws_size,
                              hipStream_t stream) {
    const float* sent1  = (const float*)d_in[0];   // (64,200,300) f32
    const float* sent2  = (const float*)d_in[1];   // (64,200,300) f32
    const float* kernel = (const float*)d_in[2];   // (16,300)     f32
    float* out = (float*)d_out;                    // (64,200,16)  f32

    char* ws = (char*)d_ws;
    float*    n1inv = (float*)ws;                  ws += (size_t)BBATCH * LL * PP * 4;   // 0.82 MB
    _Float16* n2inv = (_Float16*)ws;               ws += (size_t)BBATCH * LL * PP * 2;   // 0.41 MB
    _Float16* h1    = (_Float16*)ws;               ws += (size_t)BBATCH * LL * KG * 2;   // 8.19 MB
    _Float16* h2    = (_Float16*)ws;               ws += (size_t)BBATCH * LL * KG * 2;   // 8.19 MB
    _Float16* ksqt  = (_Float16*)ws;               // 10 KB (total ~17.6 MB)

    ksq_kernel<<<1, 256, 0, stream>>>(kernel, ksqt);

    prep_kernel<<<dim3(7, 2, BBATCH), 256, 0, stream>>>(sent1, sent2,
                                                        n1inv, n2inv, h1, h2, ksqt);

    const int lds_bytes = (200 * PS + 200 * N2S + 10 * 4 * KQS) * 2;   // 151,680 B -> 1 block/CU
    hipFuncSetAttribute((const void*)maxsim_kernel,
                        hipFuncAttributeMaxDynamicSharedMemorySize, lds_bytes);
    maxsim_kernel<<<dim3(256, 1, 1), 256, lds_bytes, stream>>>(h1, h2, ksqt, n2inv, n1inv, out);
}